// Round 1
// baseline (2048.474 us; speedup 1.0000x reference)
//
#include <hip/hip_runtime.h>
#include <cstdint>
#include <cstddef>

#define NN 50000
#define EE 800000
#define INF 512
#define HH  256
#define CC  10

// ---------------------------------------------------------------- degrees
__global__ void k_degrees(const int* __restrict__ src, const int* __restrict__ dst,
                          int* __restrict__ cnt_out, int* __restrict__ cnt_in) {
    int e = blockIdx.x * blockDim.x + threadIdx.x;
    if (e >= EE) return;
    atomicAdd(&cnt_out[src[e]], 1);
    atomicAdd(&cnt_in[dst[e]], 1);
}

__global__ void k_norms(const int* __restrict__ cnt_out, const int* __restrict__ cnt_in,
                        float* __restrict__ norm_src, float* __restrict__ norm_dst) {
    int i = blockIdx.x * blockDim.x + threadIdx.x;
    if (i >= NN) return;
    norm_src[i] = 1.0f / sqrtf(fmaxf((float)cnt_out[i], 1.0f));
    norm_dst[i] = 1.0f / sqrtf(fmaxf((float)cnt_in[i], 1.0f));
}

// ------------------------------------------------- exclusive scan (1 block)
__global__ void k_scan(const int* __restrict__ counts, int* __restrict__ off,
                       int* __restrict__ cur) {
    __shared__ int smem[1024];
    __shared__ int carry;
    if (threadIdx.x == 0) carry = 0;
    __syncthreads();
    for (int base = 0; base < NN; base += 1024) {
        int i = base + (int)threadIdx.x;
        int v = (i < NN) ? counts[i] : 0;
        smem[threadIdx.x] = v;
        __syncthreads();
        for (int ofs = 1; ofs < 1024; ofs <<= 1) {
            int t = (threadIdx.x >= (unsigned)ofs) ? smem[threadIdx.x - ofs] : 0;
            __syncthreads();
            smem[threadIdx.x] += t;
            __syncthreads();
        }
        int incl = smem[threadIdx.x];
        int excl = incl - v;
        if (i < NN) { off[i] = carry + excl; cur[i] = carry + excl; }
        __syncthreads();
        if (threadIdx.x == 1023) carry += smem[1023];
        __syncthreads();
    }
    if (threadIdx.x == 0) off[NN] = carry;
}

__global__ void k_fill(const int* __restrict__ src, const int* __restrict__ dst,
                       int* __restrict__ cur, int* __restrict__ csr_src) {
    int e = blockIdx.x * blockDim.x + threadIdx.x;
    if (e >= EE) return;
    int p = atomicAdd(&cur[dst[e]], 1);
    csr_src[p] = src[e];
}

// ---------------------------------------------------------------- GEMM
// out[NN][HH] = (A * norm[:,None]) @ W,  W is [K][HH]
template<int K>
__global__ __launch_bounds__(256) void k_gemm_scaled(
        const float* __restrict__ A, const float* __restrict__ norm,
        const float* __restrict__ W, float* __restrict__ out) {
    __shared__ float As[16][65];
    __shared__ float Bs[16][65];
    int m0 = blockIdx.x * 64;
    int n0 = blockIdx.y * 64;
    int tid = threadIdx.x;
    int tx = tid & 15, ty = tid >> 4;
    float acc[4][4] = {};
    for (int kk = 0; kk < K; kk += 16) {
        {   // A tile 64x16 -> As[k][m]
            int k = tid & 15;
            int mloc = tid >> 4;
            #pragma unroll
            for (int i = 0; i < 4; ++i) {
                int m = m0 + mloc + 16 * i;
                float v = 0.f;
                if (m < NN) v = A[(size_t)m * K + kk + k] * norm[m];
                As[k][mloc + 16 * i] = v;
            }
        }
        {   // B tile 16x64 -> Bs[k][n]
            int n = tid & 63;
            int kl = tid >> 6;        // 0..3
            #pragma unroll
            for (int i = 0; i < 4; ++i)
                Bs[kl + 4 * i][n] = W[(size_t)(kk + kl + 4 * i) * HH + n0 + n];
        }
        __syncthreads();
        #pragma unroll
        for (int k = 0; k < 16; ++k) {
            float a[4], b[4];
            #pragma unroll
            for (int i = 0; i < 4; ++i) a[i] = As[k][ty * 4 + i];
            #pragma unroll
            for (int j = 0; j < 4; ++j) b[j] = Bs[k][tx * 4 + j];
            #pragma unroll
            for (int i = 0; i < 4; ++i)
                #pragma unroll
                for (int j = 0; j < 4; ++j) acc[i][j] += a[i] * b[j];
        }
        __syncthreads();
    }
    #pragma unroll
    for (int i = 0; i < 4; ++i) {
        int m = m0 + ty * 4 + i;
        if (m >= NN) continue;
        #pragma unroll
        for (int j = 0; j < 4; ++j)
            out[(size_t)m * HH + n0 + tx * 4 + j] = acc[i][j];
    }
}

// ------------------------------------------------- SpMM + relu epilogue
// out[n][:] = relu( sum_{e in in(n)} y[src[e]][:] * norm_dst[n] + bias )
__global__ __launch_bounds__(256) void k_spmm_relu(
        const float* __restrict__ y, const int* __restrict__ off,
        const int* __restrict__ csr_src, const float* __restrict__ norm_dst,
        const float* __restrict__ bias, float* __restrict__ out) {
    int wave = threadIdx.x >> 6;
    int lane = threadIdx.x & 63;
    int n = blockIdx.x * 4 + wave;
    if (n >= NN) return;
    int s0 = off[n], s1 = off[n + 1];
    float4 acc = {0.f, 0.f, 0.f, 0.f};
    for (int e = s0; e < s1; ++e) {
        int s = csr_src[e];
        const float4 v = *(reinterpret_cast<const float4*>(y + (size_t)s * HH) + lane);
        acc.x += v.x; acc.y += v.y; acc.z += v.z; acc.w += v.w;
    }
    float nd = norm_dst[n];
    const float4 b4 = *(reinterpret_cast<const float4*>(bias) + lane);
    float4 o;
    o.x = fmaxf(acc.x * nd + b4.x, 0.f);
    o.y = fmaxf(acc.y * nd + b4.y, 0.f);
    o.z = fmaxf(acc.z * nd + b4.z, 0.f);
    o.w = fmaxf(acc.w * nd + b4.w, 0.f);
    *(reinterpret_cast<float4*>(out + (size_t)n * HH) + lane) = o;
}

// ------------------------------------------------- domain-logit accumulation
__global__ void k_dlog_init(float* __restrict__ dlog, const float* __restrict__ bd) {
    int i = blockIdx.x * blockDim.x + threadIdx.x;
    if (i >= NN) return;
    dlog[i * 2 + 0] = bd[0];
    dlog[i * 2 + 1] = bd[1];
}

// dlog[n] += h[n] (256) . Wd[row_off : row_off+256]
__global__ __launch_bounds__(256) void k_dlog_acc(
        const float* __restrict__ h, const float* __restrict__ Wd, int row_off,
        float* __restrict__ dlog) {
    int wave = threadIdx.x >> 6;
    int lane = threadIdx.x & 63;
    int n = blockIdx.x * 4 + wave;
    if (n >= NN) return;
    const float* row = h + (size_t)n * HH;
    float a0 = 0.f, a1 = 0.f;
    #pragma unroll
    for (int j = 0; j < 4; ++j) {
        int k = lane * 4 + j;
        float v = row[k];
        a0 += v * Wd[(row_off + k) * 2 + 0];
        a1 += v * Wd[(row_off + k) * 2 + 1];
    }
    #pragma unroll
    for (int o = 32; o; o >>= 1) {
        a0 += __shfl_down(a0, o);
        a1 += __shfl_down(a1, o);
    }
    if (lane == 0) {
        dlog[n * 2 + 0] += a0;
        dlog[n * 2 + 1] += a1;
    }
}

// ---------------------------------------------------------------- fc head
__global__ void k_fc(const float* __restrict__ h, const float* __restrict__ Wfc,
                     const float* __restrict__ bfc, float* __restrict__ logits) {
    int idx = blockIdx.x * blockDim.x + threadIdx.x;
    if (idx >= NN * CC) return;
    int n = idx / CC, c = idx % CC;
    const float* row = h + (size_t)n * HH;
    float a = bfc[c];
    for (int k = 0; k < HH; ++k) a += row[k] * Wfc[k * CC + c];
    logits[idx] = a;
}

__global__ void k_dlog_logits(const float* __restrict__ logits, const float* __restrict__ Wd,
                              float* __restrict__ dlog) {
    int n = blockIdx.x * blockDim.x + threadIdx.x;
    if (n >= NN) return;
    float a0 = dlog[n * 2 + 0], a1 = dlog[n * 2 + 1];
    #pragma unroll
    for (int j = 0; j < CC; ++j) {
        float v = logits[n * CC + j];
        a0 += v * Wd[(2 * HH + j) * 2 + 0];
        a1 += v * Wd[(2 * HH + j) * 2 + 1];
    }
    dlog[n * 2 + 0] = a0;
    dlog[n * 2 + 1] = a1;
}

// ---------------------------------------------------------------- losses
__global__ void k_class_loss(const float* __restrict__ logits, const int* __restrict__ labels,
                             float* __restrict__ acc) {
    int n = blockIdx.x * blockDim.x + threadIdx.x;
    if (n >= NN) return;
    const float* l = logits + n * CC;
    float m = l[0];
    #pragma unroll
    for (int j = 1; j < CC; ++j) m = fmaxf(m, l[j]);
    float s = 0.f;
    #pragma unroll
    for (int j = 0; j < CC; ++j) s += expf(l[j] - m);
    float lse = m + logf(s);
    float lp = l[labels[n]] - lse;
    atomicAdd(acc, -lp);
}

__global__ void k_domain_loss(const float* __restrict__ dlog, int label,
                              float* __restrict__ acc) {
    int n = blockIdx.x * blockDim.x + threadIdx.x;
    if (n >= NN) return;
    float l0 = dlog[n * 2 + 0], l1 = dlog[n * 2 + 1];
    float m = fmaxf(l0, l1);
    float lse = m + logf(expf(l0 - m) + expf(l1 - m));
    float lp = (label ? l1 : l0) - lse;
    atomicAdd(acc + 1, -lp);
}

__global__ void k_finalize(const float* __restrict__ acc, float* __restrict__ out) {
    out[0] = acc[0] / (float)NN + 0.01f * (acc[1] / (float)(2 * NN));
}

// ---------------------------------------------------------------- launch
extern "C" void kernel_launch(void* const* d_in, const int* in_sizes, int n_in,
                              void* d_out, int out_size, void* d_ws, size_t ws_size,
                              hipStream_t stream) {
    const float* features_s = (const float*)d_in[0];
    const int*   labels_s   = (const int*)d_in[1];
    const float* features_t = (const float*)d_in[2];
    const int*   src_s      = (const int*)d_in[3];
    const int*   dst_s      = (const int*)d_in[4];
    const int*   src_t      = (const int*)d_in[5];
    const int*   dst_t      = (const int*)d_in[6];
    const float* W0         = (const float*)d_in[7];
    const float* b0         = (const float*)d_in[8];
    const float* W1         = (const float*)d_in[9];
    const float* b1         = (const float*)d_in[10];
    const float* Wfc        = (const float*)d_in[11];
    const float* bfc        = (const float*)d_in[12];
    const float* Wd         = (const float*)d_in[13];
    const float* bd         = (const float*)d_in[14];
    float* out = (float*)d_out;

    char* w = (char*)d_ws;
    float* tmpA     = (float*)w; w += (size_t)NN * HH * 4;   // 51.2 MB
    float* tmpB     = (float*)w; w += (size_t)NN * HH * 4;   // 51.2 MB
    float* logits   = (float*)w; w += (size_t)NN * CC * 4;   // 2 MB
    float* dlog     = (float*)w; w += (size_t)NN * 2  * 4;
    float* norm_src = (float*)w; w += (size_t)NN * 4;
    float* norm_dst = (float*)w; w += (size_t)NN * 4;
    int*   cnt_out  = (int*)w;   w += (size_t)NN * 4;
    int*   cnt_in   = (int*)w;   w += (size_t)NN * 4;
    int*   csr_off  = (int*)w;   w += (size_t)(NN + 1) * 4;
    int*   csr_cur  = (int*)w;   w += (size_t)NN * 4;
    int*   csr_src  = (int*)w;   w += (size_t)EE * 4;        // 3.2 MB
    float* acc      = (float*)w; w += 16;

    hipMemsetAsync(acc, 0, 2 * sizeof(float), stream);

    const int TB = 256;
    for (int g = 0; g < 2; ++g) {
        const float* feats = g ? features_t : features_s;
        const int* src = g ? src_t : src_s;
        const int* dst = g ? dst_t : dst_s;

        hipMemsetAsync(cnt_out, 0, (size_t)NN * 4, stream);
        hipMemsetAsync(cnt_in, 0, (size_t)NN * 4, stream);
        k_degrees<<<(EE + TB - 1) / TB, TB, 0, stream>>>(src, dst, cnt_out, cnt_in);
        k_norms<<<(NN + TB - 1) / TB, TB, 0, stream>>>(cnt_out, cnt_in, norm_src, norm_dst);
        k_scan<<<1, 1024, 0, stream>>>(cnt_in, csr_off, csr_cur);
        k_fill<<<(EE + TB - 1) / TB, TB, 0, stream>>>(src, dst, csr_cur, csr_src);
        k_dlog_init<<<(NN + TB - 1) / TB, TB, 0, stream>>>(dlog, bd);

        // layer 0
        k_gemm_scaled<INF><<<dim3((NN + 63) / 64, HH / 64), TB, 0, stream>>>(feats, norm_src, W0, tmpA);
        k_spmm_relu<<<(NN + 3) / 4, TB, 0, stream>>>(tmpA, csr_off, csr_src, norm_dst, b0, tmpB);
        k_dlog_acc<<<(NN + 3) / 4, TB, 0, stream>>>(tmpB, Wd, 0, dlog);

        // layer 1
        k_gemm_scaled<HH><<<dim3((NN + 63) / 64, HH / 64), TB, 0, stream>>>(tmpB, norm_src, W1, tmpA);
        k_spmm_relu<<<(NN + 3) / 4, TB, 0, stream>>>(tmpA, csr_off, csr_src, norm_dst, b1, tmpB);
        k_dlog_acc<<<(NN + 3) / 4, TB, 0, stream>>>(tmpB, Wd, HH, dlog);

        // head
        k_fc<<<(NN * CC + TB - 1) / TB, TB, 0, stream>>>(tmpB, Wfc, bfc, logits);
        k_dlog_logits<<<(NN + TB - 1) / TB, TB, 0, stream>>>(logits, Wd, dlog);
        if (g == 0)
            k_class_loss<<<(NN + TB - 1) / TB, TB, 0, stream>>>(logits, labels_s, acc);
        k_domain_loss<<<(NN + TB - 1) / TB, TB, 0, stream>>>(dlog, g, acc);
    }
    k_finalize<<<1, 1, 0, stream>>>(acc, out);
}

// Round 2
// 1146.067 us; speedup vs baseline: 1.7874x; 1.7874x over previous
//
#include <hip/hip_runtime.h>
#include <cstdint>
#include <cstddef>

#define NN 50000
#define EE 800000
#define INF 512
#define HH  256
#define CC  10

using bfrag = __attribute__((ext_vector_type(8))) __bf16;
using f32x4 = __attribute__((ext_vector_type(4))) float;

__device__ inline unsigned short f2bf(float x) {
    unsigned u = __builtin_bit_cast(unsigned, x);
    unsigned r = u + 0x7FFFu + ((u >> 16) & 1u);
    return (unsigned short)(r >> 16);
}
__device__ inline float bf2f(unsigned short h) {
    return __builtin_bit_cast(float, (unsigned)h << 16);
}

// ---------------------------------------------------------------- casts
__global__ void k_cast_feat(const float* __restrict__ f, ushort* __restrict__ o) {
    int i = blockIdx.x * blockDim.x + threadIdx.x;   // one float4 per thread
    if (i >= NN * INF / 4) return;
    float4 v = reinterpret_cast<const float4*>(f)[i];
    ushort4 r = { f2bf(v.x), f2bf(v.y), f2bf(v.z), f2bf(v.w) };
    reinterpret_cast<ushort4*>(o)[i] = r;
}

// W [K][256] fp32 -> Wt [256][K] bf16
template<int K>
__global__ void k_cast_wt(const float* __restrict__ W, ushort* __restrict__ Wt) {
    int idx = blockIdx.x * blockDim.x + threadIdx.x;
    if (idx >= K * HH) return;
    int n = idx / K, k = idx % K;
    Wt[idx] = f2bf(W[(size_t)k * HH + n]);
}

// ---------------------------------------------------------------- degrees
__global__ void k_degrees(const int* __restrict__ src, const int* __restrict__ dst,
                          int* __restrict__ cnt_out, int* __restrict__ cnt_in) {
    int e = blockIdx.x * blockDim.x + threadIdx.x;
    if (e >= EE) return;
    atomicAdd(&cnt_out[src[e]], 1);
    atomicAdd(&cnt_in[dst[e]], 1);
}

__global__ void k_norms(const int* __restrict__ cnt_out, const int* __restrict__ cnt_in,
                        float* __restrict__ norm_src, float* __restrict__ norm_dst) {
    int i = blockIdx.x * blockDim.x + threadIdx.x;
    if (i >= NN) return;
    norm_src[i] = 1.0f / sqrtf(fmaxf((float)cnt_out[i], 1.0f));
    norm_dst[i] = 1.0f / sqrtf(fmaxf((float)cnt_in[i], 1.0f));
}

// ------------------------------------------------- exclusive scan (1 block, wave-shuffle)
__global__ void k_scan(const int* __restrict__ counts, int* __restrict__ off,
                       int* __restrict__ cur) {
    __shared__ int wsum[16];
    __shared__ int carry;
    int tid = threadIdx.x;
    int lane = tid & 63, wid = tid >> 6;
    if (tid == 0) carry = 0;
    __syncthreads();
    for (int base = 0; base < NN; base += 1024) {
        int i = base + tid;
        int v = (i < NN) ? counts[i] : 0;
        int s = v;
        #pragma unroll
        for (int o = 1; o < 64; o <<= 1) {
            int t2 = __shfl_up(s, o, 64);
            if (lane >= o) s += t2;
        }
        if (lane == 63) wsum[wid] = s;
        __syncthreads();
        if (wid == 0 && lane < 16) {
            int ws = wsum[lane];
            #pragma unroll
            for (int o = 1; o < 16; o <<= 1) {
                int t2 = __shfl_up(ws, o, 64);
                if (lane >= o) ws += t2;
            }
            wsum[lane] = ws;
        }
        __syncthreads();
        int waveoff = wid ? wsum[wid - 1] : 0;
        int excl = carry + waveoff + (s - v);
        if (i < NN) { off[i] = excl; cur[i] = excl; }
        __syncthreads();
        if (tid == 0) carry += wsum[15];
        __syncthreads();
    }
    if (tid == 0) off[NN] = carry;
}

__global__ void k_fill(const int* __restrict__ src, const int* __restrict__ dst,
                       int* __restrict__ cur, int* __restrict__ csr_src) {
    int e = blockIdx.x * blockDim.x + threadIdx.x;
    if (e >= EE) return;
    int p = atomicAdd(&cur[dst[e]], 1);
    csr_src[p] = src[e];
}

// ---------------------------------------------------------------- bf16 MFMA GEMM
// Y[M][256] = A[M][K] @ Bt[256][K]^T  (all bf16, fp32 accum), 128x128 tile, 4 waves
template<int K>
__global__ __launch_bounds__(256) void k_gemm_bf16(
        const ushort* __restrict__ A, const ushort* __restrict__ Bt,
        ushort* __restrict__ Y) {
    __shared__ ushort As[128 * 64];
    __shared__ ushort Bs[128 * 64];
    const int m0 = blockIdx.x * 128;
    const int n0 = blockIdx.y * 128;
    const int t = threadIdx.x;
    const int wid = t >> 6, lane = t & 63;
    const int wr = (wid >> 1) * 64, wc = (wid & 1) * 64;
    const int l15 = lane & 15, lg = lane >> 4;

    f32x4 acc[4][4];
    for (int m = 0; m < 4; ++m)
        for (int n = 0; n < 4; ++n)
            acc[m][n] = {0.f, 0.f, 0.f, 0.f};

    const int srow = t >> 3;       // staging row (per i-step +32)
    const int schunk = t & 7;      // 8-bf16 chunk within 64-wide row

    for (int k0 = 0; k0 < K; k0 += 64) {
        #pragma unroll
        for (int i = 0; i < 4; ++i) {
            int row = srow + i * 32;
            int sw = ((schunk ^ (row & 7)) * 8);
            int m = m0 + row; if (m >= NN) m = NN - 1;
            uint4 va = *reinterpret_cast<const uint4*>(&A[(size_t)m * K + k0 + schunk * 8]);
            *reinterpret_cast<uint4*>(&As[row * 64 + sw]) = va;
            int n = n0 + row;
            uint4 vb = *reinterpret_cast<const uint4*>(&Bt[(size_t)n * K + k0 + schunk * 8]);
            *reinterpret_cast<uint4*>(&Bs[row * 64 + sw]) = vb;
        }
        __syncthreads();
        #pragma unroll
        for (int kk = 0; kk < 64; kk += 32) {
            const int kc = kk >> 3;   // 0 or 4
            bfrag af[4], bg[4];
            #pragma unroll
            for (int m = 0; m < 4; ++m) {
                int row = wr + m * 16 + l15;
                af[m] = *reinterpret_cast<const bfrag*>(&As[row * 64 + (((lg + kc) ^ (row & 7)) * 8)]);
            }
            #pragma unroll
            for (int n = 0; n < 4; ++n) {
                int row = wc + n * 16 + l15;
                bg[n] = *reinterpret_cast<const bfrag*>(&Bs[row * 64 + (((lg + kc) ^ (row & 7)) * 8)]);
            }
            #pragma unroll
            for (int m = 0; m < 4; ++m)
                #pragma unroll
                for (int n = 0; n < 4; ++n)
                    acc[m][n] = __builtin_amdgcn_mfma_f32_16x16x32_bf16(af[m], bg[n], acc[m][n], 0, 0, 0);
        }
        __syncthreads();
    }
    #pragma unroll
    for (int m = 0; m < 4; ++m) {
        #pragma unroll
        for (int r = 0; r < 4; ++r) {
            int row = m0 + wr + m * 16 + lg * 4 + r;
            if (row >= NN) continue;
            #pragma unroll
            for (int n = 0; n < 4; ++n) {
                int col = n0 + wc + n * 16 + l15;
                Y[(size_t)row * 256 + col] = f2bf(acc[m][n][r]);
            }
        }
    }
}

// ------------------------------------------------- SpMM + relu + fused epilogues
// h[n] = relu( (sum_e y[src]*norm_src[src]) * norm_dst[n] + bias )
// dlog[n] += h[n] . Wd[ROW_OFF:ROW_OFF+256]; optionally logits[n] = h[n] @ Wfc + bfc
template<int ROW_OFF, bool DO_FC, bool STORE_H>
__global__ __launch_bounds__(256) void k_spmm_ep(
        const ushort* __restrict__ y, const int* __restrict__ off,
        const int* __restrict__ csr_src, const float* __restrict__ norm_src,
        const float* __restrict__ norm_dst, const float* __restrict__ bias,
        const float* __restrict__ Wd, const float* __restrict__ Wfc,
        const float* __restrict__ bfc, ushort* __restrict__ h_out,
        float* __restrict__ dlog, float* __restrict__ logits) {
    const int lane = threadIdx.x & 63;
    const int wid = threadIdx.x >> 6;
    const int waves = gridDim.x * 4;
    const int w0 = blockIdx.x * 4 + wid;
    const int c0 = lane * 4;

    float wd0[4], wd1[4], bia[4], wf[4][10];
    #pragma unroll
    for (int j = 0; j < 4; ++j) {
        wd0[j] = Wd[(ROW_OFF + c0 + j) * 2 + 0];
        wd1[j] = Wd[(ROW_OFF + c0 + j) * 2 + 1];
        bia[j] = bias[c0 + j];
        if (DO_FC) {
            #pragma unroll
            for (int c = 0; c < 10; ++c) wf[j][c] = Wfc[(c0 + j) * 10 + c];
        }
    }

    for (int n = w0; n < NN; n += waves) {
        int s0 = off[n], s1 = off[n + 1];
        float a0 = 0.f, a1 = 0.f, a2 = 0.f, a3 = 0.f;
        for (int e = s0; e < s1; ++e) {
            int s = csr_src[e];
            float ns = norm_src[s];
            ushort4 v = *reinterpret_cast<const ushort4*>(&y[(size_t)s * 256 + c0]);
            a0 += bf2f(v.x) * ns;
            a1 += bf2f(v.y) * ns;
            a2 += bf2f(v.z) * ns;
            a3 += bf2f(v.w) * ns;
        }
        float nd = norm_dst[n];
        float h[4] = { fmaxf(a0 * nd + bia[0], 0.f), fmaxf(a1 * nd + bia[1], 0.f),
                       fmaxf(a2 * nd + bia[2], 0.f), fmaxf(a3 * nd + bia[3], 0.f) };
        if (STORE_H) {
            ushort4 o = { f2bf(h[0]), f2bf(h[1]), f2bf(h[2]), f2bf(h[3]) };
            *reinterpret_cast<ushort4*>(&h_out[(size_t)n * 256 + c0]) = o;
        }
        float d0 = h[0] * wd0[0] + h[1] * wd0[1] + h[2] * wd0[2] + h[3] * wd0[3];
        float d1 = h[0] * wd1[0] + h[1] * wd1[1] + h[2] * wd1[2] + h[3] * wd1[3];
        #pragma unroll
        for (int o2 = 32; o2; o2 >>= 1) {
            d0 += __shfl_down(d0, o2, 64);
            d1 += __shfl_down(d1, o2, 64);
        }
        if (DO_FC) {
            float p[10];
            #pragma unroll
            for (int c = 0; c < 10; ++c)
                p[c] = h[0] * wf[0][c] + h[1] * wf[1][c] + h[2] * wf[2][c] + h[3] * wf[3][c];
            #pragma unroll
            for (int c = 0; c < 10; ++c) {
                #pragma unroll
                for (int o2 = 32; o2; o2 >>= 1) p[c] += __shfl_down(p[c], o2, 64);
            }
            if (lane == 0) {
                dlog[n * 2 + 0] += d0;
                dlog[n * 2 + 1] += d1;
                #pragma unroll
                for (int c = 0; c < 10; ++c) logits[n * 10 + c] = p[c] + bfc[c];
            }
        } else if (lane == 0) {
            dlog[n * 2 + 0] += d0;
            dlog[n * 2 + 1] += d1;
        }
    }
}

// ------------------------------------------------- dlog init / logits term
__global__ void k_dlog_init(float* __restrict__ dlog, const float* __restrict__ bd) {
    int i = blockIdx.x * blockDim.x + threadIdx.x;
    if (i >= NN) return;
    dlog[i * 2 + 0] = bd[0];
    dlog[i * 2 + 1] = bd[1];
}

__global__ void k_dlog_logits(const float* __restrict__ logits, const float* __restrict__ Wd,
                              float* __restrict__ dlog) {
    int n = blockIdx.x * blockDim.x + threadIdx.x;
    if (n >= NN) return;
    float a0 = dlog[n * 2 + 0], a1 = dlog[n * 2 + 1];
    #pragma unroll
    for (int j = 0; j < CC; ++j) {
        float v = logits[n * CC + j];
        a0 += v * Wd[(2 * HH + j) * 2 + 0];
        a1 += v * Wd[(2 * HH + j) * 2 + 1];
    }
    dlog[n * 2 + 0] = a0;
    dlog[n * 2 + 1] = a1;
}

// ---------------------------------------------------------------- losses
__global__ void k_class_loss(const float* __restrict__ logits, const int* __restrict__ labels,
                             float* __restrict__ acc) {
    int n = blockIdx.x * blockDim.x + threadIdx.x;
    float val = 0.f;
    if (n < NN) {
        const float* l = logits + n * CC;
        float m = l[0];
        #pragma unroll
        for (int j = 1; j < CC; ++j) m = fmaxf(m, l[j]);
        float s = 0.f;
        #pragma unroll
        for (int j = 0; j < CC; ++j) s += expf(l[j] - m);
        val = -(l[labels[n]] - (m + logf(s)));
    }
    #pragma unroll
    for (int o = 32; o; o >>= 1) val += __shfl_down(val, o, 64);
    if ((threadIdx.x & 63) == 0) atomicAdd(acc, val);
}

__global__ void k_domain_loss(const float* __restrict__ dlog, int label,
                              float* __restrict__ acc) {
    int n = blockIdx.x * blockDim.x + threadIdx.x;
    float val = 0.f;
    if (n < NN) {
        float l0 = dlog[n * 2 + 0], l1 = dlog[n * 2 + 1];
        float m = fmaxf(l0, l1);
        float lse = m + logf(expf(l0 - m) + expf(l1 - m));
        val = -((label ? l1 : l0) - lse);
    }
    #pragma unroll
    for (int o = 32; o; o >>= 1) val += __shfl_down(val, o, 64);
    if ((threadIdx.x & 63) == 0) atomicAdd(acc + 1, val);
}

__global__ void k_finalize(const float* __restrict__ acc, float* __restrict__ out) {
    out[0] = acc[0] / (float)NN + 0.01f * (acc[1] / (float)(2 * NN));
}

// ---------------------------------------------------------------- launch
extern "C" void kernel_launch(void* const* d_in, const int* in_sizes, int n_in,
                              void* d_out, int out_size, void* d_ws, size_t ws_size,
                              hipStream_t stream) {
    const float* features_s = (const float*)d_in[0];
    const int*   labels_s   = (const int*)d_in[1];
    const float* features_t = (const float*)d_in[2];
    const int*   src_s      = (const int*)d_in[3];
    const int*   dst_s      = (const int*)d_in[4];
    const int*   src_t      = (const int*)d_in[5];
    const int*   dst_t      = (const int*)d_in[6];
    const float* W0         = (const float*)d_in[7];
    const float* b0         = (const float*)d_in[8];
    const float* W1         = (const float*)d_in[9];
    const float* b1         = (const float*)d_in[10];
    const float* Wfc        = (const float*)d_in[11];
    const float* bfc        = (const float*)d_in[12];
    const float* Wd         = (const float*)d_in[13];
    const float* bd         = (const float*)d_in[14];
    float* out = (float*)d_out;

    auto align256 = [](size_t x) { return (x + 255) & ~(size_t)255; };
    char* w = (char*)d_ws;
    ushort* fb     = (ushort*)w; w += align256((size_t)NN * INF * 2);  // 51.2 MB
    ushort* h0     = (ushort*)w; w += align256((size_t)NN * HH * 2);   // 25.6 MB
    ushort* ybuf   = (ushort*)w; w += align256((size_t)NN * HH * 2);   // 25.6 MB
    ushort* W0t    = (ushort*)w; w += align256((size_t)INF * HH * 2);
    ushort* W1t    = (ushort*)w; w += align256((size_t)HH * HH * 2);
    float* logits  = (float*)w;  w += align256((size_t)NN * CC * 4);
    float* dlog    = (float*)w;  w += align256((size_t)NN * 2 * 4);
    float* norm_src= (float*)w;  w += align256((size_t)NN * 4);
    float* norm_dst= (float*)w;  w += align256((size_t)NN * 4);
    int*   cnt_out = (int*)w;    w += align256((size_t)NN * 4);
    int*   cnt_in  = (int*)w;    w += align256((size_t)NN * 4);
    int*   csr_off = (int*)w;    w += align256((size_t)(NN + 1) * 4);
    int*   csr_cur = (int*)w;    w += align256((size_t)NN * 4);
    int*   csr_src = (int*)w;    w += align256((size_t)EE * 4);
    float* acc     = (float*)w;  w += 256;

    hipMemsetAsync(acc, 0, 2 * sizeof(float), stream);

    const int TB = 256;
    k_cast_wt<INF><<<(INF * HH + TB - 1) / TB, TB, 0, stream>>>(W0, W0t);
    k_cast_wt<HH><<<(HH * HH + TB - 1) / TB, TB, 0, stream>>>(W1, W1t);

    const int SPMM_BLOCKS = 1563;

    for (int g = 0; g < 2; ++g) {
        const float* feats = g ? features_t : features_s;
        const int* src = g ? src_t : src_s;
        const int* dst = g ? dst_t : dst_s;

        k_cast_feat<<<(NN * INF / 4 + TB - 1) / TB, TB, 0, stream>>>(feats, fb);

        hipMemsetAsync(cnt_out, 0, (size_t)NN * 4, stream);
        hipMemsetAsync(cnt_in, 0, (size_t)NN * 4, stream);
        k_degrees<<<(EE + TB - 1) / TB, TB, 0, stream>>>(src, dst, cnt_out, cnt_in);
        k_norms<<<(NN + TB - 1) / TB, TB, 0, stream>>>(cnt_out, cnt_in, norm_src, norm_dst);
        k_scan<<<1, 1024, 0, stream>>>(cnt_in, csr_off, csr_cur);
        k_fill<<<(EE + TB - 1) / TB, TB, 0, stream>>>(src, dst, csr_cur, csr_src);
        k_dlog_init<<<(NN + TB - 1) / TB, TB, 0, stream>>>(dlog, bd);

        // layer 0: y = fb @ W0 ; h0 = relu(agg*nd + b0), dlog += h0 . Wd[0:256]
        k_gemm_bf16<INF><<<dim3((NN + 127) / 128, 2), TB, 0, stream>>>(fb, W0t, ybuf);
        k_spmm_ep<0, false, true><<<SPMM_BLOCKS, TB, 0, stream>>>(
            ybuf, csr_off, csr_src, norm_src, norm_dst, b0, Wd, Wfc, bfc, h0, dlog, logits);

        // layer 1: y = h0 @ W1 ; fused fc head + dlog += h1 . Wd[256:512]
        k_gemm_bf16<HH><<<dim3((NN + 127) / 128, 2), TB, 0, stream>>>(h0, W1t, ybuf);
        k_spmm_ep<HH, true, false><<<SPMM_BLOCKS, TB, 0, stream>>>(
            ybuf, csr_off, csr_src, norm_src, norm_dst, b1, Wd, Wfc, bfc, h0, dlog, logits);

        k_dlog_logits<<<(NN + TB - 1) / TB, TB, 0, stream>>>(logits, Wd, dlog);
        if (g == 0)
            k_class_loss<<<(NN + TB - 1) / TB, TB, 0, stream>>>(logits, labels_s, acc);
        k_domain_loss<<<(NN + TB - 1) / TB, TB, 0, stream>>>(dlog, g, acc);
    }
    k_finalize<<<1, 1, 0, stream>>>(acc, out);
}

// Round 3
// 928.406 us; speedup vs baseline: 2.2064x; 1.2344x over previous
//
#include <hip/hip_runtime.h>
#include <cstdint>
#include <cstddef>

#define NN 50000
#define EE 800000
#define INF 512
#define HH  256
#define CC  10

using bfrag = __attribute__((ext_vector_type(8))) __bf16;
using f32x4 = __attribute__((ext_vector_type(4))) float;

__device__ inline unsigned short f2bf(float x) {
    unsigned u = __builtin_bit_cast(unsigned, x);
    unsigned r = u + 0x7FFFu + ((u >> 16) & 1u);
    return (unsigned short)(r >> 16);
}
__device__ inline float bf2f(unsigned short h) {
    return __builtin_bit_cast(float, (unsigned)h << 16);
}

// ---------------------------------------------------------------- weight cast
// W [K][256] fp32 -> Wt [256][K] bf16
template<int K>
__global__ void k_cast_wt(const float* __restrict__ W, ushort* __restrict__ Wt) {
    int idx = blockIdx.x * blockDim.x + threadIdx.x;
    if (idx >= K * HH) return;
    int n = idx / K, k = idx % K;
    Wt[idx] = f2bf(W[(size_t)k * HH + n]);
}

// ---------------------------------------------------------------- degrees
__global__ void k_degrees(const int* __restrict__ src, const int* __restrict__ dst,
                          int* __restrict__ cnt_out, int* __restrict__ cnt_in) {
    int e = blockIdx.x * blockDim.x + threadIdx.x;
    if (e >= EE) return;
    atomicAdd(&cnt_out[src[e]], 1);
    atomicAdd(&cnt_in[dst[e]], 1);
}

__global__ void k_norms(const int* __restrict__ cnt_out, const int* __restrict__ cnt_in,
                        float* __restrict__ norm_src, float* __restrict__ norm_dst) {
    int i = blockIdx.x * blockDim.x + threadIdx.x;
    if (i >= NN) return;
    norm_src[i] = 1.0f / sqrtf(fmaxf((float)cnt_out[i], 1.0f));
    norm_dst[i] = 1.0f / sqrtf(fmaxf((float)cnt_in[i], 1.0f));
}

// ------------------------------------------------- exclusive scan (1 block)
__global__ void k_scan(const int* __restrict__ counts, int* __restrict__ off,
                       int* __restrict__ cur) {
    __shared__ int wsum[16];
    __shared__ int carry;
    int tid = threadIdx.x;
    int lane = tid & 63, wid = tid >> 6;
    if (tid == 0) carry = 0;
    __syncthreads();
    for (int base = 0; base < NN; base += 1024) {
        int i = base + tid;
        int v = (i < NN) ? counts[i] : 0;
        int s = v;
        #pragma unroll
        for (int o = 1; o < 64; o <<= 1) {
            int t2 = __shfl_up(s, o, 64);
            if (lane >= o) s += t2;
        }
        if (lane == 63) wsum[wid] = s;
        __syncthreads();
        if (wid == 0 && lane < 16) {
            int ws = wsum[lane];
            #pragma unroll
            for (int o = 1; o < 16; o <<= 1) {
                int t2 = __shfl_up(ws, o, 64);
                if (lane >= o) ws += t2;
            }
            wsum[lane] = ws;
        }
        __syncthreads();
        int waveoff = wid ? wsum[wid - 1] : 0;
        int excl = carry + waveoff + (s - v);
        if (i < NN) { off[i] = excl; cur[i] = excl; }
        __syncthreads();
        if (tid == 0) carry += wsum[15];
        __syncthreads();
    }
    if (tid == 0) off[NN] = carry;
}

__global__ void k_fill(const int* __restrict__ src, const int* __restrict__ dst,
                       int* __restrict__ cur, int* __restrict__ csr_src) {
    int e = blockIdx.x * blockDim.x + threadIdx.x;
    if (e >= EE) return;
    int p = atomicAdd(&cur[dst[e]], 1);
    csr_src[p] = src[e];
}

// ---------------------------------------------------------------- MFMA GEMM
// Y[M][256] = (A * ns[:,None]) @ Bt^T, bf16 MFMA, ns applied at epilogue.
// A is fp32 (F32A) or bf16. 128x128 tile, 4 waves, XOR-swizzled LDS.
template<int K, bool F32A>
__global__ __launch_bounds__(256) void k_gemm(
        const void* __restrict__ Ap, const ushort* __restrict__ Bt,
        const float* __restrict__ norm_src, ushort* __restrict__ Y) {
    __shared__ ushort As[128 * 64];
    __shared__ ushort Bs[128 * 64];
    const int m0 = blockIdx.x * 128;
    const int n0 = blockIdx.y * 128;
    const int t = threadIdx.x;
    const int wid = t >> 6, lane = t & 63;
    const int wr = (wid >> 1) * 64, wc = (wid & 1) * 64;
    const int l15 = lane & 15, lg = lane >> 4;

    f32x4 acc[4][4];
    for (int m = 0; m < 4; ++m)
        for (int n = 0; n < 4; ++n)
            acc[m][n] = {0.f, 0.f, 0.f, 0.f};

    const int srow = t >> 3;
    const int schunk = t & 7;

    for (int k0 = 0; k0 < K; k0 += 64) {
        #pragma unroll
        for (int i = 0; i < 4; ++i) {
            int row = srow + i * 32;
            int sw = ((schunk ^ (row & 7)) * 8);
            int m = m0 + row; if (m >= NN) m = NN - 1;
            uint4 va;
            if constexpr (F32A) {
                const float* ap = (const float*)Ap + (size_t)m * K + k0 + schunk * 8;
                float4 f0 = *reinterpret_cast<const float4*>(ap);
                float4 f1 = *reinterpret_cast<const float4*>(ap + 4);
                va.x = (unsigned)f2bf(f0.x) | ((unsigned)f2bf(f0.y) << 16);
                va.y = (unsigned)f2bf(f0.z) | ((unsigned)f2bf(f0.w) << 16);
                va.z = (unsigned)f2bf(f1.x) | ((unsigned)f2bf(f1.y) << 16);
                va.w = (unsigned)f2bf(f1.z) | ((unsigned)f2bf(f1.w) << 16);
            } else {
                va = *reinterpret_cast<const uint4*>((const ushort*)Ap + (size_t)m * K + k0 + schunk * 8);
            }
            *reinterpret_cast<uint4*>(&As[row * 64 + sw]) = va;
            int nb = n0 + row;
            uint4 vb = *reinterpret_cast<const uint4*>(&Bt[(size_t)nb * K + k0 + schunk * 8]);
            *reinterpret_cast<uint4*>(&Bs[row * 64 + sw]) = vb;
        }
        __syncthreads();
        #pragma unroll
        for (int kk = 0; kk < 64; kk += 32) {
            const int kc = kk >> 3;
            bfrag af[4], bg[4];
            #pragma unroll
            for (int m = 0; m < 4; ++m) {
                int row = wr + m * 16 + l15;
                af[m] = *reinterpret_cast<const bfrag*>(&As[row * 64 + (((lg + kc) ^ (row & 7)) * 8)]);
            }
            #pragma unroll
            for (int n = 0; n < 4; ++n) {
                int row = wc + n * 16 + l15;
                bg[n] = *reinterpret_cast<const bfrag*>(&Bs[row * 64 + (((lg + kc) ^ (row & 7)) * 8)]);
            }
            #pragma unroll
            for (int m = 0; m < 4; ++m)
                #pragma unroll
                for (int n = 0; n < 4; ++n)
                    acc[m][n] = __builtin_amdgcn_mfma_f32_16x16x32_bf16(af[m], bg[n], acc[m][n], 0, 0, 0);
        }
        __syncthreads();
    }
    #pragma unroll
    for (int m = 0; m < 4; ++m) {
        #pragma unroll
        for (int r = 0; r < 4; ++r) {
            int row = m0 + wr + m * 16 + lg * 4 + r;
            if (row >= NN) continue;
            float ns = norm_src[row];
            #pragma unroll
            for (int n = 0; n < 4; ++n) {
                int col = n0 + wc + n * 16 + l15;
                Y[(size_t)row * 256 + col] = f2bf(acc[m][n][r] * ns);
            }
        }
    }
}

// ------------------------------------------------- SpMM: one wave per node
// h[n] = relu( (sum_e y[src_e]) * nd[n] + bias )   (y rows pre-scaled by ns)
// lanes 0-31 gather edge e (16B/lane = full 512B row), lanes 32-63 edge e+1.
__device__ inline void add8(float* a, uint4 v) {
    a[0] += __builtin_bit_cast(float, v.x << 16);
    a[1] += __builtin_bit_cast(float, v.x & 0xffff0000u);
    a[2] += __builtin_bit_cast(float, v.y << 16);
    a[3] += __builtin_bit_cast(float, v.y & 0xffff0000u);
    a[4] += __builtin_bit_cast(float, v.z << 16);
    a[5] += __builtin_bit_cast(float, v.z & 0xffff0000u);
    a[6] += __builtin_bit_cast(float, v.w << 16);
    a[7] += __builtin_bit_cast(float, v.w & 0xffff0000u);
}

template<bool DO_DLOG>
__global__ __launch_bounds__(256) void k_spmm(
        const ushort* __restrict__ y, const int* __restrict__ off,
        const int* __restrict__ csr_src, const float* __restrict__ norm_dst,
        const float* __restrict__ bias, const float* __restrict__ Wd,
        ushort* __restrict__ h_out, float* __restrict__ dlog) {
    const int lane = threadIdx.x & 63;
    const int wid = threadIdx.x >> 6;
    const int hi = lane >> 5, l5 = lane & 31;
    const int n = blockIdx.x * 4 + wid;
    if (n >= NN) return;
    const int cg = l5 * 8;            // gather col base (8 cols / lane, 32 lanes)
    const int c0 = l5 * 8 + hi * 4;   // epilogue col base (4 cols / lane, 64 lanes)

    int s0 = off[n], s1 = off[n + 1];
    float a[8] = {0.f, 0.f, 0.f, 0.f, 0.f, 0.f, 0.f, 0.f};
    int e = s0;
    for (; e + 4 <= s1; e += 4) {
        int sA = csr_src[e + hi];
        int sB = csr_src[e + 2 + hi];
        uint4 vA = *reinterpret_cast<const uint4*>(&y[(size_t)sA * 256 + cg]);
        uint4 vB = *reinterpret_cast<const uint4*>(&y[(size_t)sB * 256 + cg]);
        add8(a, vA);
        add8(a, vB);
    }
    if (e + 2 <= s1) {
        int sA = csr_src[e + hi];
        uint4 vA = *reinterpret_cast<const uint4*>(&y[(size_t)sA * 256 + cg]);
        add8(a, vA);
        e += 2;
    }
    if (e < s1 && hi == 0) {
        int sA = csr_src[e];
        uint4 vA = *reinterpret_cast<const uint4*>(&y[(size_t)sA * 256 + cg]);
        add8(a, vA);
    }
    // merge the two edge-halves
    #pragma unroll
    for (int j = 0; j < 8; ++j) a[j] += __shfl_xor(a[j], 32, 64);
    // each lane keeps 4 of its 8 cols (upper half-wave takes the upper 4)
    float t0 = hi ? a[4] : a[0];
    float t1 = hi ? a[5] : a[1];
    float t2 = hi ? a[6] : a[2];
    float t3 = hi ? a[7] : a[3];

    float nd = norm_dst[n];
    float h[4] = { fmaxf(t0 * nd + bias[c0 + 0], 0.f),
                   fmaxf(t1 * nd + bias[c0 + 1], 0.f),
                   fmaxf(t2 * nd + bias[c0 + 2], 0.f),
                   fmaxf(t3 * nd + bias[c0 + 3], 0.f) };
    ushort4 o = { f2bf(h[0]), f2bf(h[1]), f2bf(h[2]), f2bf(h[3]) };
    *reinterpret_cast<ushort4*>(&h_out[(size_t)n * 256 + c0]) = o;

    if (DO_DLOG) {
        float d0 = 0.f, d1 = 0.f;
        #pragma unroll
        for (int j = 0; j < 4; ++j) {
            d0 += h[j] * Wd[(c0 + j) * 2 + 0];
            d1 += h[j] * Wd[(c0 + j) * 2 + 1];
        }
        #pragma unroll
        for (int o2 = 32; o2; o2 >>= 1) {
            d0 += __shfl_down(d0, o2, 64);
            d1 += __shfl_down(d1, o2, 64);
        }
        if (lane == 0) {
            dlog[n * 2 + 0] += d0;
            dlog[n * 2 + 1] += d1;
        }
    }
}

// ------------------------------------------------- dlog init
__global__ void k_dlog_init(float* __restrict__ dlog, const float* __restrict__ bd) {
    int i = blockIdx.x * blockDim.x + threadIdx.x;
    if (i >= NN) return;
    dlog[i * 2 + 0] = bd[0];
    dlog[i * 2 + 1] = bd[1];
}

// ------------------------------------------------- fused tail: fc + dlog + losses
__global__ __launch_bounds__(256) void k_tail(
        const ushort* __restrict__ h1, const float* __restrict__ Wd,
        const float* __restrict__ Wfc, const float* __restrict__ bfc,
        const int* __restrict__ labels, const float* __restrict__ dlog,
        int g, float* __restrict__ acc) {
    const int lane = threadIdx.x & 63;
    const int wid = threadIdx.x >> 6;
    const int waves = gridDim.x * 4;
    const int w0 = blockIdx.x * 4 + wid;
    const int c0 = lane * 4;

    float wd0[4], wd1[4], wf[4][10];
    #pragma unroll
    for (int j = 0; j < 4; ++j) {
        wd0[j] = Wd[(HH + c0 + j) * 2 + 0];
        wd1[j] = Wd[(HH + c0 + j) * 2 + 1];
        #pragma unroll
        for (int c = 0; c < 10; ++c) wf[j][c] = Wfc[(c0 + j) * 10 + c];
    }
    float wl0[10], wl1[10], bf[10];
    #pragma unroll
    for (int c = 0; c < 10; ++c) {
        wl0[c] = Wd[(2 * HH + c) * 2 + 0];
        wl1[c] = Wd[(2 * HH + c) * 2 + 1];
        bf[c] = bfc[c];
    }

    float cls = 0.f, dom = 0.f;
    for (int n = w0; n < NN; n += waves) {
        ushort4 v = *reinterpret_cast<const ushort4*>(&h1[(size_t)n * 256 + c0]);
        float h[4] = { bf2f(v.x), bf2f(v.y), bf2f(v.z), bf2f(v.w) };
        float d0 = h[0] * wd0[0] + h[1] * wd0[1] + h[2] * wd0[2] + h[3] * wd0[3];
        float d1 = h[0] * wd1[0] + h[1] * wd1[1] + h[2] * wd1[2] + h[3] * wd1[3];
        float p[10];
        #pragma unroll
        for (int c = 0; c < 10; ++c)
            p[c] = h[0] * wf[0][c] + h[1] * wf[1][c] + h[2] * wf[2][c] + h[3] * wf[3][c];
        #pragma unroll
        for (int o = 32; o; o >>= 1) {
            d0 += __shfl_xor(d0, o, 64);
            d1 += __shfl_xor(d1, o, 64);
            #pragma unroll
            for (int c = 0; c < 10; ++c) p[c] += __shfl_xor(p[c], o, 64);
        }
        float dl0 = dlog[n * 2 + 0] + d0;
        float dl1 = dlog[n * 2 + 1] + d1;
        float lg[10];
        #pragma unroll
        for (int c = 0; c < 10; ++c) {
            lg[c] = p[c] + bf[c];
            dl0 += lg[c] * wl0[c];
            dl1 += lg[c] * wl1[c];
        }
        if (g == 0) {
            float m = lg[0];
            #pragma unroll
            for (int c = 1; c < 10; ++c) m = fmaxf(m, lg[c]);
            float s = 0.f;
            #pragma unroll
            for (int c = 0; c < 10; ++c) s += expf(lg[c] - m);
            int lab = labels[n];
            float tgt = lg[0];
            #pragma unroll
            for (int c = 1; c < 10; ++c) tgt = (c == lab) ? lg[c] : tgt;
            cls += -(tgt - (m + logf(s)));
        }
        float m2 = fmaxf(dl0, dl1);
        float lse2 = m2 + logf(expf(dl0 - m2) + expf(dl1 - m2));
        dom += -((g ? dl1 : dl0) - lse2);
    }
    if (lane == 0) {
        if (g == 0) atomicAdd(acc, cls);
        atomicAdd(acc + 1, dom);
    }
}

__global__ void k_finalize(const float* __restrict__ acc, float* __restrict__ out) {
    out[0] = acc[0] / (float)NN + 0.01f * (acc[1] / (float)(2 * NN));
}

// ---------------------------------------------------------------- launch
extern "C" void kernel_launch(void* const* d_in, const int* in_sizes, int n_in,
                              void* d_out, int out_size, void* d_ws, size_t ws_size,
                              hipStream_t stream) {
    const float* features_s = (const float*)d_in[0];
    const int*   labels_s   = (const int*)d_in[1];
    const float* features_t = (const float*)d_in[2];
    const int*   src_s      = (const int*)d_in[3];
    const int*   dst_s      = (const int*)d_in[4];
    const int*   src_t      = (const int*)d_in[5];
    const int*   dst_t      = (const int*)d_in[6];
    const float* W0         = (const float*)d_in[7];
    const float* b0         = (const float*)d_in[8];
    const float* W1         = (const float*)d_in[9];
    const float* b1         = (const float*)d_in[10];
    const float* Wfc        = (const float*)d_in[11];
    const float* bfc        = (const float*)d_in[12];
    const float* Wd         = (const float*)d_in[13];
    const float* bd         = (const float*)d_in[14];
    float* out = (float*)d_out;

    auto align256 = [](size_t x) { return (x + 255) & ~(size_t)255; };
    char* w = (char*)d_ws;
    ushort* h0     = (ushort*)w; w += align256((size_t)NN * HH * 2);   // 25.6 MB
    ushort* ybuf   = (ushort*)w; w += align256((size_t)NN * HH * 2);   // 25.6 MB
    ushort* W0t    = (ushort*)w; w += align256((size_t)INF * HH * 2);
    ushort* W1t    = (ushort*)w; w += align256((size_t)HH * HH * 2);
    float* dlog    = (float*)w;  w += align256((size_t)NN * 2 * 4);
    float* norm_src= (float*)w;  w += align256((size_t)NN * 4);
    float* norm_dst= (float*)w;  w += align256((size_t)NN * 4);
    int*   cnt_out = (int*)w;    w += align256((size_t)NN * 4);
    int*   cnt_in  = (int*)w;    w += align256((size_t)NN * 4);
    int*   csr_off = (int*)w;    w += align256((size_t)(NN + 1) * 4);
    int*   csr_cur = (int*)w;    w += align256((size_t)NN * 4);
    int*   csr_src = (int*)w;    w += align256((size_t)EE * 4);
    float* acc     = (float*)w;  w += 256;

    hipMemsetAsync(acc, 0, 2 * sizeof(float), stream);

    const int TB = 256;
    k_cast_wt<INF><<<(INF * HH + TB - 1) / TB, TB, 0, stream>>>(W0, W0t);
    k_cast_wt<HH><<<(HH * HH + TB - 1) / TB, TB, 0, stream>>>(W1, W1t);

    for (int g = 0; g < 2; ++g) {
        const float* feats = g ? features_t : features_s;
        const int* src = g ? src_t : src_s;
        const int* dst = g ? dst_t : dst_s;
        const float* bias0 = b0, *bias1 = b1;

        hipMemsetAsync(cnt_out, 0, (size_t)NN * 4, stream);
        hipMemsetAsync(cnt_in, 0, (size_t)NN * 4, stream);
        k_degrees<<<(EE + TB - 1) / TB, TB, 0, stream>>>(src, dst, cnt_out, cnt_in);
        k_norms<<<(NN + TB - 1) / TB, TB, 0, stream>>>(cnt_out, cnt_in, norm_src, norm_dst);
        k_scan<<<1, 1024, 0, stream>>>(cnt_in, csr_off, csr_cur);
        k_fill<<<(EE + TB - 1) / TB, TB, 0, stream>>>(src, dst, csr_cur, csr_src);
        k_dlog_init<<<(NN + TB - 1) / TB, TB, 0, stream>>>(dlog, bd);

        // layer 0: ybuf = (feats*ns) @ W0 (bf16), h0 = relu(agg*nd + b0), dlog += h0.Wd[0:256]
        k_gemm<INF, true><<<dim3((NN + 127) / 128, 2), TB, 0, stream>>>(feats, W0t, norm_src, ybuf);
        k_spmm<true><<<(NN + 3) / 4, TB, 0, stream>>>(
            ybuf, csr_off, csr_src, norm_dst, bias0, Wd, h0, dlog);

        // layer 1: ybuf = (h0*ns) @ W1, h1 = relu(agg*nd + b1)  (h1 overwrites h0)
        k_gemm<HH, false><<<dim3((NN + 127) / 128, 2), TB, 0, stream>>>(h0, W1t, norm_src, ybuf);
        k_spmm<false><<<(NN + 3) / 4, TB, 0, stream>>>(
            ybuf, csr_off, csr_src, norm_dst, bias1, Wd, h0, dlog);

        // tail: fc head + dlog(h1) + logits.Wd + class/domain losses
        k_tail<<<782, TB, 0, stream>>>(h0, Wd, Wfc, bfc, labels_s, dlog, g, acc);
    }
    k_finalize<<<1, 1, 0, stream>>>(acc, out);
}

// Round 4
// 751.836 us; speedup vs baseline: 2.7246x; 1.2349x over previous
//
#include <hip/hip_runtime.h>
#include <cstdint>
#include <cstddef>

#define NN 50000
#define EE 800000
#define INF 512
#define HH  256
#define CC  10
#define NB  196   // ceil(NN/256)

using bfrag = __attribute__((ext_vector_type(8))) __bf16;
using f32x4 = __attribute__((ext_vector_type(4))) float;

__device__ inline unsigned short f2bf(float x) {
    unsigned u = __builtin_bit_cast(unsigned, x);
    unsigned r = u + 0x7FFFu + ((u >> 16) & 1u);
    return (unsigned short)(r >> 16);
}
__device__ inline float bf2f(unsigned short h) {
    return __builtin_bit_cast(float, (unsigned)h << 16);
}

// ---------------------------------------------------------------- weight casts
// W [K][256] fp32 -> Wt [256][K] bf16
template<int K>
__global__ void k_cast_wt(const float* __restrict__ W, ushort* __restrict__ Wt) {
    int idx = blockIdx.x * blockDim.x + threadIdx.x;
    if (idx >= K * HH) return;
    int n = idx / K, k = idx % K;
    Wt[idx] = f2bf(W[(size_t)k * HH + n]);
}

// Wtail[16][256]: rows 0-9 = Wfc cols, row 10/11 = Wd(second half) cols, 12-15 = 0
__global__ void k_cast_wtail(const float* __restrict__ Wfc, const float* __restrict__ Wd,
                             ushort* __restrict__ Wtail) {
    int idx = blockIdx.x * blockDim.x + threadIdx.x;
    if (idx >= 16 * HH) return;
    int n = idx >> 8, k = idx & 255;
    float v = 0.f;
    if (n < 10)       v = Wfc[(size_t)k * 10 + n];
    else if (n < 12)  v = Wd[(size_t)(HH + k) * 2 + (n - 10)];
    Wtail[idx] = f2bf(v);
}

// ---------------------------------------------------------------- degrees
__global__ void k_degrees(const int* __restrict__ src, const int* __restrict__ dst,
                          int* __restrict__ cnt_out, int* __restrict__ cnt_in) {
    int e = blockIdx.x * blockDim.x + threadIdx.x;
    if (e >= EE) return;
    atomicAdd(&cnt_out[src[e]], 1);
    atomicAdd(&cnt_in[dst[e]], 1);
}

// ------------------------------------------------- 3-phase exclusive scan
__global__ void k_scan_blk(const int* __restrict__ counts, int* __restrict__ off,
                           int* __restrict__ btot) {
    __shared__ int wsum[4];
    int tid = threadIdx.x, lane = tid & 63, wid = tid >> 6;
    int i = blockIdx.x * 256 + tid;
    int v = (i < NN) ? counts[i] : 0;
    int s = v;
    #pragma unroll
    for (int o = 1; o < 64; o <<= 1) {
        int t = __shfl_up(s, o, 64);
        if (lane >= o) s += t;
    }
    if (lane == 63) wsum[wid] = s;
    __syncthreads();
    if (tid == 0) {
        int a = 0;
        #pragma unroll
        for (int w2 = 0; w2 < 4; ++w2) { int t = wsum[w2]; wsum[w2] = a; a += t; }
        btot[blockIdx.x] = a;
    }
    __syncthreads();
    if (i < NN) off[i] = wsum[wid] + s - v;
}

__global__ void k_scan_tops(const int* __restrict__ btot, int* __restrict__ bbase,
                            int* __restrict__ off) {
    __shared__ int wsum[4];
    int tid = threadIdx.x, lane = tid & 63, wid = tid >> 6;
    int v = (tid < NB) ? btot[tid] : 0;
    int s = v;
    #pragma unroll
    for (int o = 1; o < 64; o <<= 1) {
        int t = __shfl_up(s, o, 64);
        if (lane >= o) s += t;
    }
    if (lane == 63) wsum[wid] = s;
    __syncthreads();
    if (tid == 0) {
        int a = 0;
        #pragma unroll
        for (int w2 = 0; w2 < 4; ++w2) { int t = wsum[w2]; wsum[w2] = a; a += t; }
        off[NN] = a;
    }
    __syncthreads();
    if (tid < NB) bbase[tid] = wsum[wid] + s - v;
}

// fixup + norms + dlog init + cur copy
__global__ void k_scan_fin(int* __restrict__ off, const int* __restrict__ bbase,
                           int* __restrict__ cur, const int* __restrict__ cnt_out,
                           const int* __restrict__ cnt_in, float* __restrict__ norm_src,
                           float* __restrict__ norm_dst, float* __restrict__ dlog,
                           const float* __restrict__ bd) {
    int i = blockIdx.x * blockDim.x + threadIdx.x;
    if (i >= NN) return;
    int o = off[i] + bbase[i >> 8];
    off[i] = o;
    cur[i] = o;
    norm_src[i] = 1.0f / sqrtf(fmaxf((float)cnt_out[i], 1.0f));
    norm_dst[i] = 1.0f / sqrtf(fmaxf((float)cnt_in[i], 1.0f));
    dlog[i * 2 + 0] = bd[0];
    dlog[i * 2 + 1] = bd[1];
}

__global__ void k_fill(const int* __restrict__ src, const int* __restrict__ dst,
                       int* __restrict__ cur, int* __restrict__ csr_src) {
    int e = blockIdx.x * blockDim.x + threadIdx.x;
    if (e >= EE) return;
    int p = atomicAdd(&cur[dst[e]], 1);
    csr_src[p] = src[e];
}

// ---------------------------------------------------------------- MFMA GEMM
// Y[M][256] = (A * ns[:,None]) @ Bt^T, bf16 MFMA, ns applied at epilogue.
template<int K, bool F32A>
__global__ __launch_bounds__(256) void k_gemm(
        const void* __restrict__ Ap, const ushort* __restrict__ Bt,
        const float* __restrict__ norm_src, ushort* __restrict__ Y) {
    __shared__ ushort As[128 * 64];
    __shared__ ushort Bs[128 * 64];
    const int m0 = blockIdx.x * 128;
    const int n0 = blockIdx.y * 128;
    const int t = threadIdx.x;
    const int wid = t >> 6, lane = t & 63;
    const int wr = (wid >> 1) * 64, wc = (wid & 1) * 64;
    const int l15 = lane & 15, lg = lane >> 4;

    f32x4 acc[4][4];
    for (int m = 0; m < 4; ++m)
        for (int n = 0; n < 4; ++n)
            acc[m][n] = {0.f, 0.f, 0.f, 0.f};

    const int srow = t >> 3;
    const int schunk = t & 7;

    for (int k0 = 0; k0 < K; k0 += 64) {
        #pragma unroll
        for (int i = 0; i < 4; ++i) {
            int row = srow + i * 32;
            int sw = ((schunk ^ (row & 7)) * 8);
            int m = m0 + row; if (m >= NN) m = NN - 1;
            uint4 va;
            if constexpr (F32A) {
                const float* ap = (const float*)Ap + (size_t)m * K + k0 + schunk * 8;
                float4 f0 = *reinterpret_cast<const float4*>(ap);
                float4 f1 = *reinterpret_cast<const float4*>(ap + 4);
                va.x = (unsigned)f2bf(f0.x) | ((unsigned)f2bf(f0.y) << 16);
                va.y = (unsigned)f2bf(f0.z) | ((unsigned)f2bf(f0.w) << 16);
                va.z = (unsigned)f2bf(f1.x) | ((unsigned)f2bf(f1.y) << 16);
                va.w = (unsigned)f2bf(f1.z) | ((unsigned)f2bf(f1.w) << 16);
            } else {
                va = *reinterpret_cast<const uint4*>((const ushort*)Ap + (size_t)m * K + k0 + schunk * 8);
            }
            *reinterpret_cast<uint4*>(&As[row * 64 + sw]) = va;
            int nb = n0 + row;
            uint4 vb = *reinterpret_cast<const uint4*>(&Bt[(size_t)nb * K + k0 + schunk * 8]);
            *reinterpret_cast<uint4*>(&Bs[row * 64 + sw]) = vb;
        }
        __syncthreads();
        #pragma unroll
        for (int kk = 0; kk < 64; kk += 32) {
            const int kc = kk >> 3;
            bfrag af[4], bg[4];
            #pragma unroll
            for (int m = 0; m < 4; ++m) {
                int row = wr + m * 16 + l15;
                af[m] = *reinterpret_cast<const bfrag*>(&As[row * 64 + (((lg + kc) ^ (row & 7)) * 8)]);
            }
            #pragma unroll
            for (int n = 0; n < 4; ++n) {
                int row = wc + n * 16 + l15;
                bg[n] = *reinterpret_cast<const bfrag*>(&Bs[row * 64 + (((lg + kc) ^ (row & 7)) * 8)]);
            }
            #pragma unroll
            for (int m = 0; m < 4; ++m)
                #pragma unroll
                for (int n = 0; n < 4; ++n)
                    acc[m][n] = __builtin_amdgcn_mfma_f32_16x16x32_bf16(af[m], bg[n], acc[m][n], 0, 0, 0);
        }
        __syncthreads();
    }
    #pragma unroll
    for (int m = 0; m < 4; ++m) {
        #pragma unroll
        for (int r = 0; r < 4; ++r) {
            int row = m0 + wr + m * 16 + lg * 4 + r;
            if (row >= NN) continue;
            float ns = norm_src[row];
            #pragma unroll
            for (int n = 0; n < 4; ++n) {
                int col = n0 + wc + n * 16 + l15;
                Y[(size_t)row * 256 + col] = f2bf(acc[m][n][r] * ns);
            }
        }
    }
}

// ------------------------------------------------- SpMM: one wave per node
__device__ inline void add8(float* a, uint4 v) {
    a[0] += __builtin_bit_cast(float, v.x << 16);
    a[1] += __builtin_bit_cast(float, v.x & 0xffff0000u);
    a[2] += __builtin_bit_cast(float, v.y << 16);
    a[3] += __builtin_bit_cast(float, v.y & 0xffff0000u);
    a[4] += __builtin_bit_cast(float, v.z << 16);
    a[5] += __builtin_bit_cast(float, v.z & 0xffff0000u);
    a[6] += __builtin_bit_cast(float, v.w << 16);
    a[7] += __builtin_bit_cast(float, v.w & 0xffff0000u);
}

template<bool DO_DLOG>
__global__ __launch_bounds__(256) void k_spmm(
        const ushort* __restrict__ y, const int* __restrict__ off,
        const int* __restrict__ csr_src, const float* __restrict__ norm_dst,
        const float* __restrict__ bias, const float* __restrict__ Wd,
        ushort* __restrict__ h_out, float* __restrict__ dlog) {
    const int lane = threadIdx.x & 63;
    const int wid = threadIdx.x >> 6;
    const int hi = lane >> 5, l5 = lane & 31;
    const int n = blockIdx.x * 4 + wid;
    if (n >= NN) return;
    const int cg = l5 * 8;
    const int c0 = l5 * 8 + hi * 4;

    int s0 = off[n], s1 = off[n + 1];
    float a[8] = {0.f, 0.f, 0.f, 0.f, 0.f, 0.f, 0.f, 0.f};
    int e = s0;
    for (; e + 4 <= s1; e += 4) {
        int sA = csr_src[e + hi];
        int sB = csr_src[e + 2 + hi];
        uint4 vA = *reinterpret_cast<const uint4*>(&y[(size_t)sA * 256 + cg]);
        uint4 vB = *reinterpret_cast<const uint4*>(&y[(size_t)sB * 256 + cg]);
        add8(a, vA);
        add8(a, vB);
    }
    if (e + 2 <= s1) {
        int sA = csr_src[e + hi];
        uint4 vA = *reinterpret_cast<const uint4*>(&y[(size_t)sA * 256 + cg]);
        add8(a, vA);
        e += 2;
    }
    if (e < s1 && hi == 0) {
        int sA = csr_src[e];
        uint4 vA = *reinterpret_cast<const uint4*>(&y[(size_t)sA * 256 + cg]);
        add8(a, vA);
    }
    #pragma unroll
    for (int j = 0; j < 8; ++j) a[j] += __shfl_xor(a[j], 32, 64);
    float t0 = hi ? a[4] : a[0];
    float t1 = hi ? a[5] : a[1];
    float t2 = hi ? a[6] : a[2];
    float t3 = hi ? a[7] : a[3];

    float nd = norm_dst[n];
    float h[4] = { fmaxf(t0 * nd + bias[c0 + 0], 0.f),
                   fmaxf(t1 * nd + bias[c0 + 1], 0.f),
                   fmaxf(t2 * nd + bias[c0 + 2], 0.f),
                   fmaxf(t3 * nd + bias[c0 + 3], 0.f) };
    ushort4 o = { f2bf(h[0]), f2bf(h[1]), f2bf(h[2]), f2bf(h[3]) };
    *reinterpret_cast<ushort4*>(&h_out[(size_t)n * 256 + c0]) = o;

    if (DO_DLOG) {
        float d0 = 0.f, d1 = 0.f;
        #pragma unroll
        for (int j = 0; j < 4; ++j) {
            d0 += h[j] * Wd[(c0 + j) * 2 + 0];
            d1 += h[j] * Wd[(c0 + j) * 2 + 1];
        }
        #pragma unroll
        for (int o2 = 32; o2; o2 >>= 1) {
            d0 += __shfl_down(d0, o2, 64);
            d1 += __shfl_down(d1, o2, 64);
        }
        if (lane == 0) {
            dlog[n * 2 + 0] += d0;
            dlog[n * 2 + 1] += d1;
        }
    }
}

// ------------------------------------------------- MFMA tail: fc + dlog + losses
// Per wave: 16 nodes. T[16 nodes][16 cols] = h1_tile @ Wtail^T via 8 MFMA.
// cols 0-9 = fc logits (need +bfc), col 10/11 = dlog contribution.
__global__ __launch_bounds__(256) void k_tail_mfma(
        const ushort* __restrict__ h1, const ushort* __restrict__ Wtail,
        const float* __restrict__ bfc, const int* __restrict__ labels,
        const float* __restrict__ dlog, int g, float* __restrict__ acc) {
    __shared__ float smem[4][16][17];
    const int tid = threadIdx.x;
    const int wid = tid >> 6, lane = tid & 63;
    const int l15 = lane & 15, lg = lane >> 4;
    const int base = blockIdx.x * 64 + wid * 16;

    int arow = base + l15; if (arow >= NN) arow = NN - 1;
    const ushort* ap = h1 + (size_t)arow * 256 + lg * 8;
    const ushort* bp = Wtail + (size_t)l15 * 256 + lg * 8;
    f32x4 accv = {0.f, 0.f, 0.f, 0.f};
    #pragma unroll
    for (int kk = 0; kk < 8; ++kk) {
        bfrag af = *reinterpret_cast<const bfrag*>(ap + kk * 32);
        bfrag bg = *reinterpret_cast<const bfrag*>(bp + kk * 32);
        accv = __builtin_amdgcn_mfma_f32_16x16x32_bf16(af, bg, accv, 0, 0, 0);
    }
    #pragma unroll
    for (int j = 0; j < 4; ++j) smem[wid][lg * 4 + j][l15] = accv[j];
    __syncthreads();

    float cls = 0.f, dom = 0.f;
    int n = base + lane;                 // lanes 0-15 own one node each
    if (lane < 16 && n < NN) {
        float lgt[10];
        #pragma unroll
        for (int c = 0; c < 10; ++c) lgt[c] = smem[wid][lane][c] + bfc[c];
        float dl0 = dlog[n * 2 + 0] + smem[wid][lane][10];
        float dl1 = dlog[n * 2 + 1] + smem[wid][lane][11];
        if (g == 0) {
            float m = lgt[0];
            #pragma unroll
            for (int c = 1; c < 10; ++c) m = fmaxf(m, lgt[c]);
            float s = 0.f;
            #pragma unroll
            for (int c = 0; c < 10; ++c) s += expf(lgt[c] - m);
            int lab = labels[n];
            float tgt = lgt[0];
            #pragma unroll
            for (int c = 1; c < 10; ++c) tgt = (c == lab) ? lgt[c] : tgt;
            cls = -(tgt - (m + logf(s)));
        }
        float m2 = fmaxf(dl0, dl1);
        float lse2 = m2 + logf(expf(dl0 - m2) + expf(dl1 - m2));
        dom = -((g ? dl1 : dl0) - lse2);
    }
    #pragma unroll
    for (int o = 32; o; o >>= 1) {
        cls += __shfl_xor(cls, o, 64);
        dom += __shfl_xor(dom, o, 64);
    }
    if (lane == 0) {
        if (g == 0) atomicAdd(acc, cls);
        atomicAdd(acc + 1, dom);
    }
}

__global__ void k_finalize(const float* __restrict__ acc, float* __restrict__ out) {
    out[0] = acc[0] / (float)NN + 0.01f * (acc[1] / (float)(2 * NN));
}

// ---------------------------------------------------------------- launch
extern "C" void kernel_launch(void* const* d_in, const int* in_sizes, int n_in,
                              void* d_out, int out_size, void* d_ws, size_t ws_size,
                              hipStream_t stream) {
    const float* features_s = (const float*)d_in[0];
    const int*   labels_s   = (const int*)d_in[1];
    const float* features_t = (const float*)d_in[2];
    const int*   src_s      = (const int*)d_in[3];
    const int*   dst_s      = (const int*)d_in[4];
    const int*   src_t      = (const int*)d_in[5];
    const int*   dst_t      = (const int*)d_in[6];
    const float* W0         = (const float*)d_in[7];
    const float* b0         = (const float*)d_in[8];
    const float* W1         = (const float*)d_in[9];
    const float* b1         = (const float*)d_in[10];
    const float* Wfc        = (const float*)d_in[11];
    const float* bfc        = (const float*)d_in[12];
    const float* Wd         = (const float*)d_in[13];
    const float* bd         = (const float*)d_in[14];
    float* out = (float*)d_out;

    auto align256 = [](size_t x) { return (x + 255) & ~(size_t)255; };
    char* w = (char*)d_ws;
    ushort* h0     = (ushort*)w; w += align256((size_t)NN * HH * 2);   // 25.6 MB
    ushort* ybuf   = (ushort*)w; w += align256((size_t)NN * HH * 2);   // 25.6 MB
    ushort* W0t    = (ushort*)w; w += align256((size_t)INF * HH * 2);
    ushort* W1t    = (ushort*)w; w += align256((size_t)HH * HH * 2);
    ushort* Wtail  = (ushort*)w; w += align256((size_t)16 * HH * 2);
    float* dlog    = (float*)w;  w += align256((size_t)NN * 2 * 4);
    float* norm_src= (float*)w;  w += align256((size_t)NN * 4);
    float* norm_dst= (float*)w;  w += align256((size_t)NN * 4);
    int*   cnt     = (int*)w;    w += align256((size_t)2 * NN * 4);
    int*   csr_off = (int*)w;    w += align256((size_t)(NN + 1) * 4);
    int*   csr_cur = (int*)w;    w += align256((size_t)NN * 4);
    int*   csr_src = (int*)w;    w += align256((size_t)EE * 4);
    int*   btot    = (int*)w;    w += align256((size_t)NB * 4);
    int*   bbase   = (int*)w;    w += align256((size_t)NB * 4);
    float* acc     = (float*)w;  w += 256;
    int* cnt_out = cnt;
    int* cnt_in  = cnt + NN;

    hipMemsetAsync(acc, 0, 2 * sizeof(float), stream);

    const int TB = 256;
    k_cast_wt<INF><<<(INF * HH + TB - 1) / TB, TB, 0, stream>>>(W0, W0t);
    k_cast_wt<HH><<<(HH * HH + TB - 1) / TB, TB, 0, stream>>>(W1, W1t);
    k_cast_wtail<<<(16 * HH + TB - 1) / TB, TB, 0, stream>>>(Wfc, Wd, Wtail);

    for (int g = 0; g < 2; ++g) {
        const float* feats = g ? features_t : features_s;
        const int* src = g ? src_t : src_s;
        const int* dst = g ? dst_t : dst_s;

        hipMemsetAsync(cnt, 0, (size_t)2 * NN * 4, stream);
        k_degrees<<<(EE + TB - 1) / TB, TB, 0, stream>>>(src, dst, cnt_out, cnt_in);
        k_scan_blk<<<NB, TB, 0, stream>>>(cnt_in, csr_off, btot);
        k_scan_tops<<<1, TB, 0, stream>>>(btot, bbase, csr_off);
        k_scan_fin<<<NB, TB, 0, stream>>>(csr_off, bbase, csr_cur, cnt_out, cnt_in,
                                          norm_src, norm_dst, dlog, bd);
        k_fill<<<(EE + TB - 1) / TB, TB, 0, stream>>>(src, dst, csr_cur, csr_src);

        // layer 0
        k_gemm<INF, true><<<dim3((NN + 127) / 128, 2), TB, 0, stream>>>(feats, W0t, norm_src, ybuf);
        k_spmm<true><<<(NN + 3) / 4, TB, 0, stream>>>(
            ybuf, csr_off, csr_src, norm_dst, b0, Wd, h0, dlog);

        // layer 1
        k_gemm<HH, false><<<dim3((NN + 127) / 128, 2), TB, 0, stream>>>(h0, W1t, norm_src, ybuf);
        k_spmm<false><<<(NN + 3) / 4, TB, 0, stream>>>(
            ybuf, csr_off, csr_src, norm_dst, b1, Wd, h0, dlog);

        // fc head + dlog + losses (MFMA tail)
        k_tail_mfma<<<(NN + 63) / 64, TB, 0, stream>>>(h0, Wtail, bfc, labels_s, dlog, g, acc);
    }
    k_finalize<<<1, 1, 0, stream>>>(acc, out);
}